// Round 7
// baseline (1654.820 us; speedup 1.0000x reference)
//
#include <hip/hip_runtime.h>
#include <math.h>

#define CDIM 768

typedef __attribute__((ext_vector_type(8))) _Float16 h8;
typedef __attribute__((ext_vector_type(4))) _Float16 h4;
typedef __attribute__((ext_vector_type(4))) float f4;

template <int SRC> struct EltT;                     // source element type
template <> struct EltT<0> { using t = float; };    // fp32, cvt on the fly
template <> struct EltT<1> { using t = _Float16; }; // fp16 direct

// ---------------- reductions (256-thread blocks, 4 waves) ----------------
__device__ __forceinline__ float block_reduce_sum(float v, float* sm) {
#pragma unroll
  for (int o = 32; o > 0; o >>= 1) v += __shfl_down(v, o, 64);
  const int lane = threadIdx.x & 63, wid = threadIdx.x >> 6;
  __syncthreads();  // protect prior use of sm
  if (lane == 0) sm[wid] = v;
  __syncthreads();
  return sm[0] + sm[1] + sm[2] + sm[3];
}

__device__ __forceinline__ float block_reduce_max(float v, float* sm) {
#pragma unroll
  for (int o = 32; o > 0; o >>= 1) v = fmaxf(v, __shfl_down(v, o, 64));
  const int lane = threadIdx.x & 63, wid = threadIdx.x >> 6;
  __syncthreads();
  if (lane == 0) sm[wid] = v;
  __syncthreads();
  return fmaxf(fmaxf(sm[0], sm[1]), fmaxf(sm[2], sm[3]));
}

__device__ __forceinline__ float softplusf(float x) {
  return (x > 0.f) ? x + log1pf(expf(-x)) : log1pf(expf(x));
}

// ---------------- fp32 -> fp16 streaming convert (x4 vector) ----------------
__global__ __launch_bounds__(256) void cvt16(const float* __restrict__ x,
                                             _Float16* __restrict__ o, int n4) {
  for (int i = blockIdx.x * 256 + threadIdx.x; i < n4; i += gridDim.x * 256) {
    const float4 v = ((const float4*)x)[i];
    h4 h;
    h[0] = (_Float16)v.x; h[1] = (_Float16)v.y;
    h[2] = (_Float16)v.z; h[3] = (_Float16)v.w;
    ((h4*)o)[i] = h;
  }
}

__device__ __forceinline__ h8 cvt8(const float4 u, const float4 v) {
  h8 r;
  r[0] = (_Float16)u.x; r[1] = (_Float16)u.y;
  r[2] = (_Float16)u.z; r[3] = (_Float16)u.w;
  r[4] = (_Float16)v.x; r[5] = (_Float16)v.y;
  r[6] = (_Float16)v.z; r[7] = (_Float16)v.w;
  return r;
}

// ================= fp16 MFMA NT GEMM, 128x128 tile, BK=32 =================
// C[m,n] = sum_k A[m,k]*B[n,k]  (A:[M,K], B:[N,K] row-major).
// 256 thr = 4 waves (2x2), per-wave 64x64 via 4x4 frags of 16x16x32 MFMA.
// SRC 0: fp32 inputs converted during staging; SRC 1: fp16 direct.
// Frag layouts verified on HW (round 6 pass): A/B lane holds 8 contiguous k
// at k=(lane>>4)*8, row/col=lane&15; C/D col=lane&15, row=(lane>>4)*4+reg.
// EPI: 1 = Q: H1=fp16(acc+bias), H2=fp16((acc+bias)^2)
//      5 = O1 = g*(acc+bias) + (1-g)*resid, g=sigmoid(gate[0])
//      7 = fused KV proj (N=3072; bias=bk, resid=bv, sC=voff halves):
//          seg=colg/768 (block-uniform): 0 -> H1=fp16(mu_k)
//          1 -> H2=fp16(softplus+1e-6); 2 -> O1=fp32 mu_v
//          3 -> H2[sC+.]=fp16(softplus+1e-6)
template <int SRC, int EPI>
__global__ __launch_bounds__(256) void hgemm_nt(
    const void* __restrict__ Av, const void* __restrict__ Bv,
    const float* __restrict__ bias, float* __restrict__ O1, int M, int N,
    int K, long sA, long sB, long sC, _Float16* __restrict__ H1,
    _Float16* __restrict__ H2, const float* __restrict__ resid,
    const float* __restrict__ gate) {
  using AT = typename EltT<SRC>::t;
  __shared__ _Float16 As[128][40], Bs[128][40];
  const int t = threadIdx.x;
  const int z = blockIdx.z;
  const AT* pA = (const AT*)Av + (size_t)z * sA;
  const AT* pB = (const AT*)Bv + (size_t)z * sB;
  float* pC = O1 + (size_t)z * sC;
  const int bm = blockIdx.y * 128, bn = blockIdx.x * 128;
  const int lane = t & 63, w = t >> 6;
  const int wr = w >> 1, wc = w & 1;
  const int lr = lane & 15, kb = (lane >> 4) * 8;
  const int r0 = t >> 2, kc0 = (t & 3) * 8;
  const int r1 = (t + 256) >> 2, kc1 = ((t + 256) & 3) * 8;
  const AT* gA0 = pA + (size_t)(bm + r0) * K + kc0;
  const AT* gA1 = pA + (size_t)(bm + r1) * K + kc1;
  const AT* gB0 = pB + (size_t)(bn + r0) * K + kc0;
  const AT* gB1 = pB + (size_t)(bn + r1) * K + kc1;
  f4 acc[4][4];
#pragma unroll
  for (int i = 0; i < 4; ++i)
#pragma unroll
    for (int j = 0; j < 4; ++j) acc[i][j] = (f4){0.f, 0.f, 0.f, 0.f};
  float4 fA0u, fA0v, fA1u, fA1v, fB0u, fB0v, fB1u, fB1v;
  h8 hA0, hA1, hB0, hB1;
  if constexpr (SRC == 0) {
    fA0u = *(const float4*)(gA0); fA0v = *(const float4*)(gA0 + 4);
    fA1u = *(const float4*)(gA1); fA1v = *(const float4*)(gA1 + 4);
    fB0u = *(const float4*)(gB0); fB0v = *(const float4*)(gB0 + 4);
    fB1u = *(const float4*)(gB1); fB1v = *(const float4*)(gB1 + 4);
  } else {
    hA0 = *(const h8*)(gA0); hA1 = *(const h8*)(gA1);
    hB0 = *(const h8*)(gB0); hB1 = *(const h8*)(gB1);
  }
  for (int kk = 0; kk < K; kk += 32) {
    __syncthreads();
    if constexpr (SRC == 0) {
      *(h8*)&As[r0][kc0] = cvt8(fA0u, fA0v);
      *(h8*)&As[r1][kc1] = cvt8(fA1u, fA1v);
      *(h8*)&Bs[r0][kc0] = cvt8(fB0u, fB0v);
      *(h8*)&Bs[r1][kc1] = cvt8(fB1u, fB1v);
    } else {
      *(h8*)&As[r0][kc0] = hA0; *(h8*)&As[r1][kc1] = hA1;
      *(h8*)&Bs[r0][kc0] = hB0; *(h8*)&Bs[r1][kc1] = hB1;
    }
    __syncthreads();
    if (kk + 32 < K) {
      const int o = kk + 32;
      if constexpr (SRC == 0) {
        fA0u = *(const float4*)(gA0 + o); fA0v = *(const float4*)(gA0 + o + 4);
        fA1u = *(const float4*)(gA1 + o); fA1v = *(const float4*)(gA1 + o + 4);
        fB0u = *(const float4*)(gB0 + o); fB0v = *(const float4*)(gB0 + o + 4);
        fB1u = *(const float4*)(gB1 + o); fB1v = *(const float4*)(gB1 + o + 4);
      } else {
        hA0 = *(const h8*)(gA0 + o); hA1 = *(const h8*)(gA1 + o);
        hB0 = *(const h8*)(gB0 + o); hB1 = *(const h8*)(gB1 + o);
      }
    }
    h8 fa[4], fb[4];
#pragma unroll
    for (int i = 0; i < 4; ++i)
      fa[i] = *(const h8*)&As[wr * 64 + i * 16 + lr][kb];
#pragma unroll
    for (int j = 0; j < 4; ++j)
      fb[j] = *(const h8*)&Bs[wc * 64 + j * 16 + lr][kb];
#pragma unroll
    for (int i = 0; i < 4; ++i)
#pragma unroll
      for (int j = 0; j < 4; ++j)
        acc[i][j] = __builtin_amdgcn_mfma_f32_16x16x32_f16(fa[i], fb[j],
                                                           acc[i][j], 0, 0, 0);
  }
  float g_ = 0.f, og_ = 0.f;
  if constexpr (EPI == 5) {
    g_ = 1.f / (1.f + expf(-gate[0]));
    og_ = 1.f - g_;
  }
#pragma unroll
  for (int i = 0; i < 4; ++i)
#pragma unroll
    for (int j = 0; j < 4; ++j) {
      const int colg = bn + wc * 64 + j * 16 + lr;
      float bcol = 0.f;
      if constexpr (EPI == 1 || EPI == 5) bcol = bias[colg];
#pragma unroll
      for (int r = 0; r < 4; ++r) {
        const int rowg = bm + wr * 64 + i * 16 + (lane >> 4) * 4 + r;
        const float v = acc[i][j][r];
        if constexpr (EPI == 1) {
          const size_t idx = (size_t)rowg * N + colg;
          const float tq = v + bcol;
          H1[idx] = (_Float16)tq;
          H2[idx] = (_Float16)(tq * tq);
        } else if constexpr (EPI == 5) {
          const size_t idx = (size_t)rowg * N + colg;
          pC[idx] = g_ * (v + bcol) + og_ * resid[idx];
        } else if constexpr (EPI == 7) {
          const int seg = colg / 768;             // block-uniform (768%128==0)
          const int c = colg - seg * 768;
          const float bc = (seg < 2 ? bias : resid)[colg - (seg >> 1) * 1536];
          const float tv = v + bc;
          const size_t oidx = (size_t)rowg * 768 + c;
          if (seg == 0)      H1[oidx] = (_Float16)tv;
          else if (seg == 1) H2[oidx] = (_Float16)(softplusf(tv) + 1e-6f);
          else if (seg == 2) O1[oidx] = tv;
          else  H2[(size_t)sC + oidx] = (_Float16)(softplusf(tv) + 1e-6f);
        }
      }
    }
}

// ======= fused scores: S = fp16( QK/sqrt(C) - 2.35*sqrt(Q2*Kvar/C) ) =======
// Dual-accumulator 128x128, BK=32, batched z=8. Same frag layout as hgemm.
__global__ __launch_bounds__(256) void scores_fused(
    const _Float16* __restrict__ Q, const _Float16* __restrict__ Q2,
    const _Float16* __restrict__ Kmu, const _Float16* __restrict__ Kvar,
    _Float16* __restrict__ S) {
  __shared__ _Float16 A1s[128][40], A2s[128][40], B1s[128][40], B2s[128][40];
  const int t = threadIdx.x;
  const int z = blockIdx.z;
  const _Float16* pA1 = Q + (size_t)z * 786432;
  const _Float16* pA2 = Q2 + (size_t)z * 786432;
  const _Float16* pB1 = Kmu + (size_t)z * 1572864;
  const _Float16* pB2 = Kvar + (size_t)z * 1572864;
  _Float16* pS = S + (size_t)z * 2097152;
  const int bm = blockIdx.y * 128, bn = blockIdx.x * 128;
  const int lane = t & 63, w = t >> 6;
  const int wr = w >> 1, wc = w & 1;
  const int lr = lane & 15, kb = (lane >> 4) * 8;
  const int r0 = t >> 2, kc0 = (t & 3) * 8;
  const int r1 = (t + 256) >> 2, kc1 = ((t + 256) & 3) * 8;
  const _Float16* gA10 = pA1 + (size_t)(bm + r0) * 768 + kc0;
  const _Float16* gA11 = pA1 + (size_t)(bm + r1) * 768 + kc1;
  const _Float16* gA20 = pA2 + (size_t)(bm + r0) * 768 + kc0;
  const _Float16* gA21 = pA2 + (size_t)(bm + r1) * 768 + kc1;
  const _Float16* gB10 = pB1 + (size_t)(bn + r0) * 768 + kc0;
  const _Float16* gB11 = pB1 + (size_t)(bn + r1) * 768 + kc1;
  const _Float16* gB20 = pB2 + (size_t)(bn + r0) * 768 + kc0;
  const _Float16* gB21 = pB2 + (size_t)(bn + r1) * 768 + kc1;
  f4 acc1[4][4], acc2[4][4];
#pragma unroll
  for (int i = 0; i < 4; ++i)
#pragma unroll
    for (int j = 0; j < 4; ++j) {
      acc1[i][j] = (f4){0.f, 0.f, 0.f, 0.f};
      acc2[i][j] = (f4){0.f, 0.f, 0.f, 0.f};
    }
  h8 a10 = *(const h8*)gA10, a11 = *(const h8*)gA11;
  h8 a20 = *(const h8*)gA20, a21 = *(const h8*)gA21;
  h8 b10 = *(const h8*)gB10, b11 = *(const h8*)gB11;
  h8 b20 = *(const h8*)gB20, b21 = *(const h8*)gB21;
  for (int kk = 0; kk < 768; kk += 32) {
    __syncthreads();
    *(h8*)&A1s[r0][kc0] = a10; *(h8*)&A1s[r1][kc1] = a11;
    *(h8*)&A2s[r0][kc0] = a20; *(h8*)&A2s[r1][kc1] = a21;
    *(h8*)&B1s[r0][kc0] = b10; *(h8*)&B1s[r1][kc1] = b11;
    *(h8*)&B2s[r0][kc0] = b20; *(h8*)&B2s[r1][kc1] = b21;
    __syncthreads();
    if (kk + 32 < 768) {
      const int o = kk + 32;
      a10 = *(const h8*)(gA10 + o); a11 = *(const h8*)(gA11 + o);
      a20 = *(const h8*)(gA20 + o); a21 = *(const h8*)(gA21 + o);
      b10 = *(const h8*)(gB10 + o); b11 = *(const h8*)(gB11 + o);
      b20 = *(const h8*)(gB20 + o); b21 = *(const h8*)(gB21 + o);
    }
    h8 fa1[4], fa2[4];
#pragma unroll
    for (int i = 0; i < 4; ++i) {
      fa1[i] = *(const h8*)&A1s[wr * 64 + i * 16 + lr][kb];
      fa2[i] = *(const h8*)&A2s[wr * 64 + i * 16 + lr][kb];
    }
#pragma unroll
    for (int j = 0; j < 4; ++j) {
      const h8 fb1 = *(const h8*)&B1s[wc * 64 + j * 16 + lr][kb];
      const h8 fb2 = *(const h8*)&B2s[wc * 64 + j * 16 + lr][kb];
#pragma unroll
      for (int i = 0; i < 4; ++i) {
        acc1[i][j] = __builtin_amdgcn_mfma_f32_16x16x32_f16(fa1[i], fb1,
                                                            acc1[i][j], 0, 0, 0);
        acc2[i][j] = __builtin_amdgcn_mfma_f32_16x16x32_f16(fa2[i], fb2,
                                                            acc2[i][j], 0, 0, 0);
      }
    }
  }
  const float INV_SCALE = 0.03608439182435161f;  // 1/sqrt(768)
  const float INV_C = 1.0f / 768.0f;
#pragma unroll
  for (int i = 0; i < 4; ++i)
#pragma unroll
    for (int j = 0; j < 4; ++j) {
      const int colg = bn + wc * 64 + j * 16 + lr;
#pragma unroll
      for (int r = 0; r < 4; ++r) {
        const int rowg = bm + wr * 64 + i * 16 + (lane >> 4) * 4 + r;
        const float s = acc1[i][j][r] * INV_SCALE -
                        2.35f * sqrtf(fmaxf(acc2[i][j][r], 0.f) * INV_C);
        pS[(size_t)rowg * 2048 + colg] = (_Float16)s;
      }
    }
}

// ---- K post: kmuF = fp16(LN(kRawF16)) ----
__global__ __launch_bounds__(256) void ln_post_k(
    const _Float16* __restrict__ kraw, const float* __restrict__ lng,
    const float* __restrict__ lnb, _Float16* __restrict__ kmuF) {
  __shared__ float sm[4];
  const size_t r = blockIdx.x;
  const _Float16* mu = kraw + r * 768;
  const int t = threadIdx.x;
  const float x0 = (float)mu[t], x1 = (float)mu[t + 256],
              x2 = (float)mu[t + 512];
  const float mean = block_reduce_sum(x0 + x1 + x2, sm) * (1.0f / 768.0f);
  const float d0 = x0 - mean, d1 = x1 - mean, d2 = x2 - mean;
  const float var =
      block_reduce_sum(d0 * d0 + d1 * d1 + d2 * d2, sm) * (1.0f / 768.0f);
  const float inv = rsqrtf(var + 1e-5f);
  _Float16* om = kmuF + r * 768;
  om[t]       = (_Float16)(d0 * inv * lng[t] + lnb[t]);
  om[t + 256] = (_Float16)(d1 * inv * lng[t + 256] + lnb[t + 256]);
  om[t + 512] = (_Float16)(d2 * inv * lng[t + 512] + lnb[t + 512]);
}

// ---- V post: Vs = LN(muRaw) + sqrt(vvarF)*eps, fp32 in-place over muRaw ----
__global__ __launch_bounds__(256) void ln_post_v(
    float* __restrict__ muRaw, const _Float16* __restrict__ vvarF,
    const float* __restrict__ lng, const float* __restrict__ lnb,
    const float* __restrict__ eps) {
  __shared__ float sm[4];
  const size_t r = blockIdx.x;
  float* mu = muRaw + r * 768;
  const _Float16* vf = vvarF + r * 768;
  const int t = threadIdx.x;
  const float x0 = mu[t], x1 = mu[t + 256], x2 = mu[t + 512];
  const float mean = block_reduce_sum(x0 + x1 + x2, sm) * (1.0f / 768.0f);
  const float d0 = x0 - mean, d1 = x1 - mean, d2 = x2 - mean;
  const float var =
      block_reduce_sum(d0 * d0 + d1 * d1 + d2 * d2, sm) * (1.0f / 768.0f);
  const float inv = rsqrtf(var + 1e-5f);
  const float y0 = d0 * inv * lng[t] + lnb[t];
  const float y1 = d1 * inv * lng[t + 256] + lnb[t + 256];
  const float y2 = d2 * inv * lng[t + 512] + lnb[t + 512];
  const float* er = eps + r * 768;
  mu[t]       = y0 + sqrtf((float)vf[t]) * er[t];
  mu[t + 256] = y1 + sqrtf((float)vf[t + 256]) * er[t + 256];
  mu[t + 512] = y2 + sqrtf((float)vf[t + 512]) * er[t + 512];
}

// ---------------- row softmax over 2048 fp16, in place ----------------
__global__ __launch_bounds__(256) void softmax_rows_f16(_Float16* __restrict__ S) {
  __shared__ float sm[4];
  _Float16* row = S + (size_t)blockIdx.x * 2048;
  const int t = threadIdx.x;
  h8 v = *(h8*)(row + t * 8);
  float f[8];
#pragma unroll
  for (int c = 0; c < 8; ++c) f[c] = (float)v[c];
  float mx = f[0];
#pragma unroll
  for (int c = 1; c < 8; ++c) mx = fmaxf(mx, f[c]);
  mx = block_reduce_max(mx, sm);
  float s = 0.f;
#pragma unroll
  for (int c = 0; c < 8; ++c) {
    f[c] = expf(f[c] - mx);
    s += f[c];
  }
  s = block_reduce_sum(s, sm);
  const float rcp = 1.0f / s;
#pragma unroll
  for (int c = 0; c < 8; ++c) v[c] = (_Float16)(f[c] * rcp);
  *(h8*)(row + t * 8) = v;
}

// --- attn(fp16) @ V_sample(fp32): batched NN GEMM, 128x128, fp32 FMA ---
__global__ __launch_bounds__(256) void gemm_nn_av(const _Float16* __restrict__ S,
                                                  const float* __restrict__ V,
                                                  float* __restrict__ O) {
  __shared__ float As[16][132], Bs[16][132];
  const int b = blockIdx.z;
  const _Float16* Sb = S + (size_t)b * 1024 * 2048;
  const float* Vb = V + (size_t)b * 2048 * CDIM;
  float* Ob = O + (size_t)b * 1024 * CDIM;
  const int t = threadIdx.x, tx = t & 15, ty = t >> 4;
  const int bm = blockIdx.y * 128, bc = blockIdx.x * 128;
  const int lr = t >> 2, lc = (t & 3) << 2;   // A loader (transpose to LDS)
  const int vr = t >> 5, vc = (t & 31) << 2;  // B loader (direct, 8+8 rows)
  const _Float16* Sp0 = Sb + (size_t)(bm + lr) * 2048 + lc;
  const _Float16* Sp1 = Sb + (size_t)(bm + 64 + lr) * 2048 + lc;
  const float* Vp0 = Vb + (size_t)vr * CDIM + bc + vc;
  const float* Vp1 = Vb + (size_t)(8 + vr) * CDIM + bc + vc;
  float acc[8][8] = {};
  h4 a0 = *(const h4*)(Sp0);
  h4 a1 = *(const h4*)(Sp1);
  float4 b0 = *(const float4*)(Vp0);
  float4 b1 = *(const float4*)(Vp1);
  for (int k0 = 0; k0 < 2048; k0 += 16) {
    __syncthreads();
    As[lc + 0][lr] = (float)a0[0]; As[lc + 1][lr] = (float)a0[1];
    As[lc + 2][lr] = (float)a0[2]; As[lc + 3][lr] = (float)a0[3];
    As[lc + 0][64 + lr] = (float)a1[0]; As[lc + 1][64 + lr] = (float)a1[1];
    As[lc + 2][64 + lr] = (float)a1[2]; As[lc + 3][64 + lr] = (float)a1[3];
    *(float4*)&Bs[vr][vc] = b0;
    *(float4*)&Bs[8 + vr][vc] = b1;
    __syncthreads();
    if (k0 + 16 < 2048) {
      a0 = *(const h4*)(Sp0 + k0 + 16);
      a1 = *(const h4*)(Sp1 + k0 + 16);
      b0 = *(const float4*)(Vp0 + (size_t)(k0 + 16) * CDIM);
      b1 = *(const float4*)(Vp1 + (size_t)(k0 + 16) * CDIM);
    }
#pragma unroll
    for (int k = 0; k < 16; ++k) {
      const float4 x0 = *(const float4*)&As[k][ty << 2];
      const float4 x1 = *(const float4*)&As[k][64 + (ty << 2)];
      const float4 y0 = *(const float4*)&Bs[k][tx << 2];
      const float4 y1 = *(const float4*)&Bs[k][64 + (tx << 2)];
      const float ar[8] = {x0.x, x0.y, x0.z, x0.w, x1.x, x1.y, x1.z, x1.w};
      const float br[8] = {y0.x, y0.y, y0.z, y0.w, y1.x, y1.y, y1.z, y1.w};
#pragma unroll
      for (int i = 0; i < 8; ++i)
#pragma unroll
        for (int j = 0; j < 8; ++j) acc[i][j] = fmaf(ar[i], br[j], acc[i][j]);
    }
  }
#pragma unroll
  for (int i = 0; i < 8; ++i) {
    const int m = bm + ((i < 4) ? ((ty << 2) + i) : (64 + (ty << 2) + i - 4));
    float* op0 = Ob + (size_t)m * CDIM + bc + (tx << 2);
    float* op1 = Ob + (size_t)m * CDIM + bc + 64 + (tx << 2);
    float4 o0, o1;
    o0.x = acc[i][0]; o0.y = acc[i][1]; o0.z = acc[i][2]; o0.w = acc[i][3];
    o1.x = acc[i][4]; o1.y = acc[i][5]; o1.z = acc[i][6]; o1.w = acc[i][7];
    *(float4*)op0 = o0;
    *(float4*)op1 = o1;
  }
}

// ---------------- launch ----------------
extern "C" void kernel_launch(void* const* d_in, const int* in_sizes, int n_in,
                              void* d_out, int out_size, void* d_ws,
                              size_t ws_size, hipStream_t stream) {
  const float* query   = (const float*)d_in[0];
  const float* context = (const float*)d_in[1];
  const float* eps     = (const float*)d_in[2];
  const float* Wq      = (const float*)d_in[3];
  const float* bq      = (const float*)d_in[4];
  const float* Wk      = (const float*)d_in[5];
  const float* bk      = (const float*)d_in[6];
  const float* Wv      = (const float*)d_in[7];
  const float* bv      = (const float*)d_in[8];
  const float* Wo      = (const float*)d_in[9];
  const float* bo      = (const float*)d_in[10];
  const float* ln_k_g  = (const float*)d_in[11];
  const float* ln_k_b  = (const float*)d_in[12];
  const float* ln_v_g  = (const float*)d_in[13];
  const float* ln_v_b  = (const float*)d_in[14];
  const float* gate    = (const float*)d_in[15];

  // ---- workspace map, NEED = 189,267,968 B. Lifetimes ([step..step]):
  //  @0          ctxF f16 25.2M [1..2]; then qF @0 + q2F @12582912 [5..6]
  //  @25165824   wkvF f16 4.7M [1..2]
  //  @29884416   kRawF16 25.2M [2..3]; then Obuf f32 25.2M [8..9]
  //  @55050240   kmuF f16 25.2M [3..6]
  //  @80216064   kvarF f16 25.2M [2..6]   (vvarF = kvarF + 12,582,912 halves)
  //  @105381888  vvarF f16 25.2M [2..4]; then S/attn f16 33.5M [6..8]
  //  @138936320  vmuRaw/Vs f32 50.3M [2..8]
  const size_t NEED = 189267968ull;
  if (ws_size < NEED) return;  // fail safely (no OOB writes)
  char* wsb = (char*)d_ws;
  _Float16* ctxF  = (_Float16*)(wsb);
  _Float16* qF    = (_Float16*)(wsb);
  _Float16* q2F   = (_Float16*)(wsb + 12582912);
  _Float16* wkvF  = (_Float16*)(wsb + 25165824);
  _Float16* kRawF = (_Float16*)(wsb + 29884416);
  float*    Obuf  = (float*)(wsb + 29884416);
  _Float16* kmuF  = (_Float16*)(wsb + 55050240);
  _Float16* kvarF = (_Float16*)(wsb + 80216064);
  _Float16* vvarF = (_Float16*)(wsb + 105381888);
  _Float16* Sf    = (_Float16*)(wsb + 105381888);
  float*    vmuB  = (float*)(wsb + 138936320);

  const dim3 blk(256);
  auto sgrid = [](int n4) {
    int g = (n4 + 255) / 256;
    return dim3(g > 2048 ? 2048 : g);
  };
  // 1. upfront fp16 conversion: context, [Wk;Wv] stacked
  cvt16<<<sgrid(3145728), blk, 0, stream>>>(context, ctxF, 3145728);
  cvt16<<<sgrid(294912), blk, 0, stream>>>(Wk, wkvF, 294912);
  cvt16<<<sgrid(294912), blk, 0, stream>>>(Wv, wkvF + 1179648, 294912);
  // 2. fused K+V projection (N=3072): kRawF, kvarF, vmuB, vvarF
  //    (bias=bk, resid=bv, sC = vvar offset in halves from kvarF)
  hgemm_nt<1, 7><<<dim3(24, 128, 1), blk, 0, stream>>>(
      ctxF, wkvF, bk, vmuB, 16384, 3072, 768, 0, 0, 12582912,
      kRawF, kvarF, bv, nullptr);
  // 3. K LN -> kmuF fp16
  ln_post_k<<<dim3(16384), blk, 0, stream>>>(kRawF, ln_k_g, ln_k_b, kmuF);
  // 4. V post: Vs = LN(vmu) + sqrt(vvar)*eps, in-place fp32
  ln_post_v<<<dim3(16384), blk, 0, stream>>>(vmuB, vvarF, ln_v_g, ln_v_b, eps);
  // 5. Q proj (fp32 src): qF = fp16(Q), q2F = fp16(Q^2)
  hgemm_nt<0, 1><<<dim3(6, 64, 1), blk, 0, stream>>>(
      query, Wq, bq, nullptr, 8192, 768, 768, 0, 0, 0, qF, q2F, nullptr,
      nullptr);
  // 6. fused scores -> Sf fp16 (batched z=8)
  scores_fused<<<dim3(16, 8, 8), blk, 0, stream>>>(qF, q2F, kmuF, kvarF, Sf);
  // 7. softmax rows fp16, in place -> attn
  softmax_rows_f16<<<dim3(8192), blk, 0, stream>>>(Sf);
  // 8. O = attn @ Vs -> Obuf fp32
  gemm_nn_av<<<dim3(6, 8, 8), blk, 0, stream>>>(Sf, vmuB, Obuf);
  // 9. final: d_out = g*(O @ Wo^T + bo) + (1-g)*query
  hgemm_nt<0, 5><<<dim3(6, 64, 1), blk, 0, stream>>>(
      Obuf, Wo, bo, (float*)d_out, 8192, 768, 768, 0, 0, 0, nullptr, nullptr,
      query, gate);
}

// Round 8
// 1094.474 us; speedup vs baseline: 1.5120x; 1.5120x over previous
//
#include <hip/hip_runtime.h>
#include <math.h>

#define CDIM 768

typedef __attribute__((ext_vector_type(8))) _Float16 h8;
typedef __attribute__((ext_vector_type(4))) _Float16 h4;
typedef __attribute__((ext_vector_type(4))) float f4;

template <int SRC> struct EltT;                     // source element type
template <> struct EltT<0> { using t = float; };    // fp32, cvt on the fly
template <> struct EltT<1> { using t = _Float16; }; // fp16 direct

// ---------------- reductions (256-thread blocks, 4 waves) ----------------
__device__ __forceinline__ float block_reduce_sum(float v, float* sm) {
#pragma unroll
  for (int o = 32; o > 0; o >>= 1) v += __shfl_down(v, o, 64);
  const int lane = threadIdx.x & 63, wid = threadIdx.x >> 6;
  __syncthreads();  // protect prior use of sm
  if (lane == 0) sm[wid] = v;
  __syncthreads();
  return sm[0] + sm[1] + sm[2] + sm[3];
}

__device__ __forceinline__ float block_reduce_max(float v, float* sm) {
#pragma unroll
  for (int o = 32; o > 0; o >>= 1) v = fmaxf(v, __shfl_down(v, o, 64));
  const int lane = threadIdx.x & 63, wid = threadIdx.x >> 6;
  __syncthreads();
  if (lane == 0) sm[wid] = v;
  __syncthreads();
  return fmaxf(fmaxf(sm[0], sm[1]), fmaxf(sm[2], sm[3]));
}

__device__ __forceinline__ float softplusf(float x) {
  return (x > 0.f) ? x + log1pf(expf(-x)) : log1pf(expf(x));
}

// ---------------- fp32 -> fp16 streaming convert (x4 vector) ----------------
__global__ __launch_bounds__(256) void cvt16(const float* __restrict__ x,
                                             _Float16* __restrict__ o, int n4) {
  for (int i = blockIdx.x * 256 + threadIdx.x; i < n4; i += gridDim.x * 256) {
    const float4 v = ((const float4*)x)[i];
    h4 h;
    h[0] = (_Float16)v.x; h[1] = (_Float16)v.y;
    h[2] = (_Float16)v.z; h[3] = (_Float16)v.w;
    ((h4*)o)[i] = h;
  }
}

__device__ __forceinline__ h8 cvt8(const float4 u, const float4 v) {
  h8 r;
  r[0] = (_Float16)u.x; r[1] = (_Float16)u.y;
  r[2] = (_Float16)u.z; r[3] = (_Float16)u.w;
  r[4] = (_Float16)v.x; r[5] = (_Float16)v.y;
  r[6] = (_Float16)v.z; r[7] = (_Float16)v.w;
  return r;
}

// ================= fp16 MFMA NT GEMM, 128x128 tile, BK=32 =================
// C[m,n] = sum_k A[m,k]*B[n,k]  (A:[M,K], B:[N,K] row-major).
// 256 thr = 4 waves (2x2), per-wave 64x64 via 4x4 frags of 16x16x32 MFMA.
// SRC 0: fp32 inputs converted during staging; SRC 1: fp16 direct.
// Frag layouts HW-verified (round 6 pass).
// fp16 tile outputs go through an LDS transpose (union over the dead A/B
// staging buffers) and are stored as contiguous 256B rows of h8 — round 7
// counters showed per-lane scattered 2B stores cause ~40x HBM write
// amplification (WRITE_SIZE 4.86 GB vs 126 MB logical); 4B scattered fp32
// stores are clean (round 6 control), so fp32 outputs store directly.
// EPI: 1 = Q: H1=fp16(acc+bias), H2=fp16((acc+bias)^2)
//      5 = O1 = g*(acc+bias) + (1-g)*resid, g=sigmoid(gate[0])  [fp32 direct]
//      7 = fused KV proj (N=3072; bias=bk, resid=bv, sC=voff halves):
//          seg=bn/768 (block-uniform): 0 -> H1=fp16(mu_k raw)
//          1 -> H2=fp16(softplus+1e-6); 2 -> O1=fp32 mu_v [direct]
//          3 -> H2[sC+.]=fp16(softplus+1e-6)
template <int SRC, int EPI>
__global__ __launch_bounds__(256) void hgemm_nt(
    const void* __restrict__ Av, const void* __restrict__ Bv,
    const float* __restrict__ bias, float* __restrict__ O1, int M, int N,
    int K, long sA, long sB, long sC, _Float16* __restrict__ H1,
    _Float16* __restrict__ H2, const float* __restrict__ resid,
    const float* __restrict__ gate) {
  using AT = typename EltT<SRC>::t;
  __shared__ union LdsU {
    struct { _Float16 A[128][40]; _Float16 B[128][40]; } ab;  // 20480 B
    _Float16 E[128][136];                                     // 34816 B
  } lds;
  _Float16 (&As)[128][40] = lds.ab.A;
  _Float16 (&Bs)[128][40] = lds.ab.B;
  const int t = threadIdx.x;
  const int z = blockIdx.z;
  const AT* pA = (const AT*)Av + (size_t)z * sA;
  const AT* pB = (const AT*)Bv + (size_t)z * sB;
  float* pC = O1 + (size_t)z * sC;
  const int bm = blockIdx.y * 128, bn = blockIdx.x * 128;
  const int lane = t & 63, w = t >> 6;
  const int wr = w >> 1, wc = w & 1;
  const int lr = lane & 15, kb = (lane >> 4) * 8;
  const int r0 = t >> 2, kc0 = (t & 3) * 8;
  const int r1 = (t + 256) >> 2, kc1 = ((t + 256) & 3) * 8;
  const AT* gA0 = pA + (size_t)(bm + r0) * K + kc0;
  const AT* gA1 = pA + (size_t)(bm + r1) * K + kc1;
  const AT* gB0 = pB + (size_t)(bn + r0) * K + kc0;
  const AT* gB1 = pB + (size_t)(bn + r1) * K + kc1;
  f4 acc[4][4];
#pragma unroll
  for (int i = 0; i < 4; ++i)
#pragma unroll
    for (int j = 0; j < 4; ++j) acc[i][j] = (f4){0.f, 0.f, 0.f, 0.f};
  float4 fA0u, fA0v, fA1u, fA1v, fB0u, fB0v, fB1u, fB1v;
  h8 hA0, hA1, hB0, hB1;
  if constexpr (SRC == 0) {
    fA0u = *(const float4*)(gA0); fA0v = *(const float4*)(gA0 + 4);
    fA1u = *(const float4*)(gA1); fA1v = *(const float4*)(gA1 + 4);
    fB0u = *(const float4*)(gB0); fB0v = *(const float4*)(gB0 + 4);
    fB1u = *(const float4*)(gB1); fB1v = *(const float4*)(gB1 + 4);
  } else {
    hA0 = *(const h8*)(gA0); hA1 = *(const h8*)(gA1);
    hB0 = *(const h8*)(gB0); hB1 = *(const h8*)(gB1);
  }
  for (int kk = 0; kk < K; kk += 32) {
    __syncthreads();
    if constexpr (SRC == 0) {
      *(h8*)&As[r0][kc0] = cvt8(fA0u, fA0v);
      *(h8*)&As[r1][kc1] = cvt8(fA1u, fA1v);
      *(h8*)&Bs[r0][kc0] = cvt8(fB0u, fB0v);
      *(h8*)&Bs[r1][kc1] = cvt8(fB1u, fB1v);
    } else {
      *(h8*)&As[r0][kc0] = hA0; *(h8*)&As[r1][kc1] = hA1;
      *(h8*)&Bs[r0][kc0] = hB0; *(h8*)&Bs[r1][kc1] = hB1;
    }
    __syncthreads();
    if (kk + 32 < K) {
      const int o = kk + 32;
      if constexpr (SRC == 0) {
        fA0u = *(const float4*)(gA0 + o); fA0v = *(const float4*)(gA0 + o + 4);
        fA1u = *(const float4*)(gA1 + o); fA1v = *(const float4*)(gA1 + o + 4);
        fB0u = *(const float4*)(gB0 + o); fB0v = *(const float4*)(gB0 + o + 4);
        fB1u = *(const float4*)(gB1 + o); fB1v = *(const float4*)(gB1 + o + 4);
      } else {
        hA0 = *(const h8*)(gA0 + o); hA1 = *(const h8*)(gA1 + o);
        hB0 = *(const h8*)(gB0 + o); hB1 = *(const h8*)(gB1 + o);
      }
    }
    h8 fa[4], fb[4];
#pragma unroll
    for (int i = 0; i < 4; ++i)
      fa[i] = *(const h8*)&As[wr * 64 + i * 16 + lr][kb];
#pragma unroll
    for (int j = 0; j < 4; ++j)
      fb[j] = *(const h8*)&Bs[wc * 64 + j * 16 + lr][kb];
#pragma unroll
    for (int i = 0; i < 4; ++i)
#pragma unroll
      for (int j = 0; j < 4; ++j)
        acc[i][j] = __builtin_amdgcn_mfma_f32_16x16x32_f16(fa[i], fb[j],
                                                           acc[i][j], 0, 0, 0);
  }
  // ---------------- epilogue ----------------
  if constexpr (EPI == 5) {  // fp32 direct (4B scattered = clean)
    const float g_ = 1.f / (1.f + expf(-gate[0]));
    const float og_ = 1.f - g_;
#pragma unroll
    for (int i = 0; i < 4; ++i)
#pragma unroll
      for (int j = 0; j < 4; ++j) {
        const int colg = bn + wc * 64 + j * 16 + lr;
        const float bcol = bias[colg];
#pragma unroll
        for (int r = 0; r < 4; ++r) {
          const int rowg = bm + wr * 64 + i * 16 + (lane >> 4) * 4 + r;
          const size_t idx = (size_t)rowg * N + colg;
          pC[idx] = g_ * (acc[i][j][r] + bcol) + og_ * resid[idx];
        }
      }
  }
  if constexpr (EPI == 7) {
    const int seg = bn / 768;  // block-uniform (tile never spans a boundary)
    if (seg == 2) {            // V-mu: fp32 direct
#pragma unroll
      for (int i = 0; i < 4; ++i)
#pragma unroll
        for (int j = 0; j < 4; ++j) {
          const int colg = bn + wc * 64 + j * 16 + lr;
          const float bc = resid[colg - 1536];  // bv[0..767]
#pragma unroll
          for (int r = 0; r < 4; ++r) {
            const int rowg = bm + wr * 64 + i * 16 + (lane >> 4) * 4 + r;
            O1[(size_t)rowg * 768 + (colg - 1536)] = acc[i][j][r] + bc;
          }
        }
    } else {  // fp16 outputs via LDS transpose (full-line stores)
      __syncthreads();  // A/B staging dead; safe to overwrite union
#pragma unroll
      for (int i = 0; i < 4; ++i)
#pragma unroll
        for (int j = 0; j < 4; ++j) {
          const int colg = bn + wc * 64 + j * 16 + lr;
          const float bc = (seg < 2 ? bias : resid)[colg - (seg >> 1) * 1536];
          const int cl = wc * 64 + j * 16 + lr;
#pragma unroll
          for (int r = 0; r < 4; ++r) {
            const int rl = wr * 64 + i * 16 + (lane >> 4) * 4 + r;
            const float tv = acc[i][j][r] + bc;
            lds.E[rl][cl] = (seg == 0) ? (_Float16)tv
                                       : (_Float16)(softplusf(tv) + 1e-6f);
          }
        }
      __syncthreads();
      _Float16* dst = (seg == 0) ? H1 : ((seg == 1) ? H2 : H2 + sC);
      const int cb = bn - seg * 768;
      for (int c = t; c < 2048; c += 256) {
        const int row = c >> 4, c8 = (c & 15) << 3;
        *(h8*)(dst + (size_t)(bm + row) * 768 + cb + c8) =
            *(const h8*)&lds.E[row][c8];
      }
    }
  }
  if constexpr (EPI == 1) {  // two fp16 tiles: q then q^2, both via LDS
    __syncthreads();
#pragma unroll
    for (int i = 0; i < 4; ++i)
#pragma unroll
      for (int j = 0; j < 4; ++j) {
        const int colg = bn + wc * 64 + j * 16 + lr;
        const float bc = bias[colg];
        const int cl = wc * 64 + j * 16 + lr;
#pragma unroll
        for (int r = 0; r < 4; ++r) {
          const int rl = wr * 64 + i * 16 + (lane >> 4) * 4 + r;
          lds.E[rl][cl] = (_Float16)(acc[i][j][r] + bc);
        }
      }
    __syncthreads();
    for (int c = t; c < 2048; c += 256) {
      const int row = c >> 4, c8 = (c & 15) << 3;
      *(h8*)(H1 + (size_t)(bm + row) * N + bn + c8) = *(const h8*)&lds.E[row][c8];
    }
    __syncthreads();
#pragma unroll
    for (int i = 0; i < 4; ++i)
#pragma unroll
      for (int j = 0; j < 4; ++j) {
        const int colg = bn + wc * 64 + j * 16 + lr;
        const float bc = bias[colg];
        const int cl = wc * 64 + j * 16 + lr;
#pragma unroll
        for (int r = 0; r < 4; ++r) {
          const int rl = wr * 64 + i * 16 + (lane >> 4) * 4 + r;
          const float tq = acc[i][j][r] + bc;
          lds.E[rl][cl] = (_Float16)(tq * tq);
        }
      }
    __syncthreads();
    for (int c = t; c < 2048; c += 256) {
      const int row = c >> 4, c8 = (c & 15) << 3;
      *(h8*)(H2 + (size_t)(bm + row) * N + bn + c8) = *(const h8*)&lds.E[row][c8];
    }
  }
}

// ======= fused scores: S = fp16( QK/sqrt(C) - 2.35*sqrt(Q2*Kvar/C) ) =======
// Dual-accumulator 128x128, BK=32, batched z=8. fp16 S written via the same
// LDS-transpose full-line path.
__global__ __launch_bounds__(256) void scores_fused(
    const _Float16* __restrict__ Q, const _Float16* __restrict__ Q2,
    const _Float16* __restrict__ Kmu, const _Float16* __restrict__ Kvar,
    _Float16* __restrict__ S) {
  __shared__ union LdsU {
    struct { _Float16 A1[128][40], A2[128][40], B1[128][40], B2[128][40]; } ab;
    _Float16 E[128][136];
  } lds;
  _Float16 (&A1s)[128][40] = lds.ab.A1;
  _Float16 (&A2s)[128][40] = lds.ab.A2;
  _Float16 (&B1s)[128][40] = lds.ab.B1;
  _Float16 (&B2s)[128][40] = lds.ab.B2;
  const int t = threadIdx.x;
  const int z = blockIdx.z;
  const _Float16* pA1 = Q + (size_t)z * 786432;
  const _Float16* pA2 = Q2 + (size_t)z * 786432;
  const _Float16* pB1 = Kmu + (size_t)z * 1572864;
  const _Float16* pB2 = Kvar + (size_t)z * 1572864;
  _Float16* pS = S + (size_t)z * 2097152;
  const int bm = blockIdx.y * 128, bn = blockIdx.x * 128;
  const int lane = t & 63, w = t >> 6;
  const int wr = w >> 1, wc = w & 1;
  const int lr = lane & 15, kb = (lane >> 4) * 8;
  const int r0 = t >> 2, kc0 = (t & 3) * 8;
  const int r1 = (t + 256) >> 2, kc1 = ((t + 256) & 3) * 8;
  const _Float16* gA10 = pA1 + (size_t)(bm + r0) * 768 + kc0;
  const _Float16* gA11 = pA1 + (size_t)(bm + r1) * 768 + kc1;
  const _Float16* gA20 = pA2 + (size_t)(bm + r0) * 768 + kc0;
  const _Float16* gA21 = pA2 + (size_t)(bm + r1) * 768 + kc1;
  const _Float16* gB10 = pB1 + (size_t)(bn + r0) * 768 + kc0;
  const _Float16* gB11 = pB1 + (size_t)(bn + r1) * 768 + kc1;
  const _Float16* gB20 = pB2 + (size_t)(bn + r0) * 768 + kc0;
  const _Float16* gB21 = pB2 + (size_t)(bn + r1) * 768 + kc1;
  f4 acc1[4][4], acc2[4][4];
#pragma unroll
  for (int i = 0; i < 4; ++i)
#pragma unroll
    for (int j = 0; j < 4; ++j) {
      acc1[i][j] = (f4){0.f, 0.f, 0.f, 0.f};
      acc2[i][j] = (f4){0.f, 0.f, 0.f, 0.f};
    }
  h8 a10 = *(const h8*)gA10, a11 = *(const h8*)gA11;
  h8 a20 = *(const h8*)gA20, a21 = *(const h8*)gA21;
  h8 b10 = *(const h8*)gB10, b11 = *(const h8*)gB11;
  h8 b20 = *(const h8*)gB20, b21 = *(const h8*)gB21;
  for (int kk = 0; kk < 768; kk += 32) {
    __syncthreads();
    *(h8*)&A1s[r0][kc0] = a10; *(h8*)&A1s[r1][kc1] = a11;
    *(h8*)&A2s[r0][kc0] = a20; *(h8*)&A2s[r1][kc1] = a21;
    *(h8*)&B1s[r0][kc0] = b10; *(h8*)&B1s[r1][kc1] = b11;
    *(h8*)&B2s[r0][kc0] = b20; *(h8*)&B2s[r1][kc1] = b21;
    __syncthreads();
    if (kk + 32 < 768) {
      const int o = kk + 32;
      a10 = *(const h8*)(gA10 + o); a11 = *(const h8*)(gA11 + o);
      a20 = *(const h8*)(gA20 + o); a21 = *(const h8*)(gA21 + o);
      b10 = *(const h8*)(gB10 + o); b11 = *(const h8*)(gB11 + o);
      b20 = *(const h8*)(gB20 + o); b21 = *(const h8*)(gB21 + o);
    }
    h8 fa1[4], fa2[4];
#pragma unroll
    for (int i = 0; i < 4; ++i) {
      fa1[i] = *(const h8*)&A1s[wr * 64 + i * 16 + lr][kb];
      fa2[i] = *(const h8*)&A2s[wr * 64 + i * 16 + lr][kb];
    }
#pragma unroll
    for (int j = 0; j < 4; ++j) {
      const h8 fb1 = *(const h8*)&B1s[wc * 64 + j * 16 + lr][kb];
      const h8 fb2 = *(const h8*)&B2s[wc * 64 + j * 16 + lr][kb];
#pragma unroll
      for (int i = 0; i < 4; ++i) {
        acc1[i][j] = __builtin_amdgcn_mfma_f32_16x16x32_f16(fa1[i], fb1,
                                                            acc1[i][j], 0, 0, 0);
        acc2[i][j] = __builtin_amdgcn_mfma_f32_16x16x32_f16(fa2[i], fb2,
                                                            acc2[i][j], 0, 0, 0);
      }
    }
  }
  const float INV_SCALE = 0.03608439182435161f;  // 1/sqrt(768)
  const float INV_C = 1.0f / 768.0f;
  __syncthreads();  // staging dead; overwrite union
#pragma unroll
  for (int i = 0; i < 4; ++i)
#pragma unroll
    for (int j = 0; j < 4; ++j) {
      const int cl = wc * 64 + j * 16 + lr;
#pragma unroll
      for (int r = 0; r < 4; ++r) {
        const int rl = wr * 64 + i * 16 + (lane >> 4) * 4 + r;
        const float s = acc1[i][j][r] * INV_SCALE -
                        2.35f * sqrtf(fmaxf(acc2[i][j][r], 0.f) * INV_C);
        lds.E[rl][cl] = (_Float16)s;
      }
    }
  __syncthreads();
  for (int c = t; c < 2048; c += 256) {
    const int row = c >> 4, c8 = (c & 15) << 3;
    *(h8*)(pS + (size_t)(bm + row) * 2048 + bn + c8) = *(const h8*)&lds.E[row][c8];
  }
}

// ---- K post: kmuF = fp16(LN(kRawF16)) ----
__global__ __launch_bounds__(256) void ln_post_k(
    const _Float16* __restrict__ kraw, const float* __restrict__ lng,
    const float* __restrict__ lnb, _Float16* __restrict__ kmuF) {
  __shared__ float sm[4];
  const size_t r = blockIdx.x;
  const _Float16* mu = kraw + r * 768;
  const int t = threadIdx.x;
  const float x0 = (float)mu[t], x1 = (float)mu[t + 256],
              x2 = (float)mu[t + 512];
  const float mean = block_reduce_sum(x0 + x1 + x2, sm) * (1.0f / 768.0f);
  const float d0 = x0 - mean, d1 = x1 - mean, d2 = x2 - mean;
  const float var =
      block_reduce_sum(d0 * d0 + d1 * d1 + d2 * d2, sm) * (1.0f / 768.0f);
  const float inv = rsqrtf(var + 1e-5f);
  _Float16* om = kmuF + r * 768;
  om[t]       = (_Float16)(d0 * inv * lng[t] + lnb[t]);
  om[t + 256] = (_Float16)(d1 * inv * lng[t + 256] + lnb[t + 256]);
  om[t + 512] = (_Float16)(d2 * inv * lng[t + 512] + lnb[t + 512]);
}

// ---- V post: Vs = LN(muRaw) + sqrt(vvarF)*eps, fp32 in-place over muRaw ----
__global__ __launch_bounds__(256) void ln_post_v(
    float* __restrict__ muRaw, const _Float16* __restrict__ vvarF,
    const float* __restrict__ lng, const float* __restrict__ lnb,
    const float* __restrict__ eps) {
  __shared__ float sm[4];
  const size_t r = blockIdx.x;
  float* mu = muRaw + r * 768;
  const _Float16* vf = vvarF + r * 768;
  const int t = threadIdx.x;
  const float x0 = mu[t], x1 = mu[t + 256], x2 = mu[t + 512];
  const float mean = block_reduce_sum(x0 + x1 + x2, sm) * (1.0f / 768.0f);
  const float d0 = x0 - mean, d1 = x1 - mean, d2 = x2 - mean;
  const float var =
      block_reduce_sum(d0 * d0 + d1 * d1 + d2 * d2, sm) * (1.0f / 768.0f);
  const float inv = rsqrtf(var + 1e-5f);
  const float y0 = d0 * inv * lng[t] + lnb[t];
  const float y1 = d1 * inv * lng[t + 256] + lnb[t + 256];
  const float y2 = d2 * inv * lng[t + 512] + lnb[t + 512];
  const float* er = eps + r * 768;
  mu[t]       = y0 + sqrtf((float)vf[t]) * er[t];
  mu[t + 256] = y1 + sqrtf((float)vf[t + 256]) * er[t + 256];
  mu[t + 512] = y2 + sqrtf((float)vf[t + 512]) * er[t + 512];
}

// ---------------- row softmax over 2048 fp16, in place ----------------
__global__ __launch_bounds__(256) void softmax_rows_f16(_Float16* __restrict__ S) {
  __shared__ float sm[4];
  _Float16* row = S + (size_t)blockIdx.x * 2048;
  const int t = threadIdx.x;
  h8 v = *(h8*)(row + t * 8);
  float f[8];
#pragma unroll
  for (int c = 0; c < 8; ++c) f[c] = (float)v[c];
  float mx = f[0];
#pragma unroll
  for (int c = 1; c < 8; ++c) mx = fmaxf(mx, f[c]);
  mx = block_reduce_max(mx, sm);
  float s = 0.f;
#pragma unroll
  for (int c = 0; c < 8; ++c) {
    f[c] = expf(f[c] - mx);
    s += f[c];
  }
  s = block_reduce_sum(s, sm);
  const float rcp = 1.0f / s;
#pragma unroll
  for (int c = 0; c < 8; ++c) v[c] = (_Float16)(f[c] * rcp);
  *(h8*)(row + t * 8) = v;
}

// --- attn(fp16) @ V_sample(fp32): batched NN GEMM, 128x128, fp32 FMA ---
__global__ __launch_bounds__(256) void gemm_nn_av(const _Float16* __restrict__ S,
                                                  const float* __restrict__ V,
                                                  float* __restrict__ O) {
  __shared__ float As[16][132], Bs[16][132];
  const int b = blockIdx.z;
  const _Float16* Sb = S + (size_t)b * 1024 * 2048;
  const float* Vb = V + (size_t)b * 2048 * CDIM;
  float* Ob = O + (size_t)b * 1024 * CDIM;
  const int t = threadIdx.x, tx = t & 15, ty = t >> 4;
  const int bm = blockIdx.y * 128, bc = blockIdx.x * 128;
  const int lr = t >> 2, lc = (t & 3) << 2;   // A loader (transpose to LDS)
  const int vr = t >> 5, vc = (t & 31) << 2;  // B loader (direct, 8+8 rows)
  const _Float16* Sp0 = Sb + (size_t)(bm + lr) * 2048 + lc;
  const _Float16* Sp1 = Sb + (size_t)(bm + 64 + lr) * 2048 + lc;
  const float* Vp0 = Vb + (size_t)vr * CDIM + bc + vc;
  const float* Vp1 = Vb + (size_t)(8 + vr) * CDIM + bc + vc;
  float acc[8][8] = {};
  h4 a0 = *(const h4*)(Sp0);
  h4 a1 = *(const h4*)(Sp1);
  float4 b0 = *(const float4*)(Vp0);
  float4 b1 = *(const float4*)(Vp1);
  for (int k0 = 0; k0 < 2048; k0 += 16) {
    __syncthreads();
    As[lc + 0][lr] = (float)a0[0]; As[lc + 1][lr] = (float)a0[1];
    As[lc + 2][lr] = (float)a0[2]; As[lc + 3][lr] = (float)a0[3];
    As[lc + 0][64 + lr] = (float)a1[0]; As[lc + 1][64 + lr] = (float)a1[1];
    As[lc + 2][64 + lr] = (float)a1[2]; As[lc + 3][64 + lr] = (float)a1[3];
    *(float4*)&Bs[vr][vc] = b0;
    *(float4*)&Bs[8 + vr][vc] = b1;
    __syncthreads();
    if (k0 + 16 < 2048) {
      a0 = *(const h4*)(Sp0 + k0 + 16);
      a1 = *(const h4*)(Sp1 + k0 + 16);
      b0 = *(const float4*)(Vp0 + (size_t)(k0 + 16) * CDIM);
      b1 = *(const float4*)(Vp1 + (size_t)(k0 + 16) * CDIM);
    }
#pragma unroll
    for (int k = 0; k < 16; ++k) {
      const float4 x0 = *(const float4*)&As[k][ty << 2];
      const float4 x1 = *(const float4*)&As[k][64 + (ty << 2)];
      const float4 y0 = *(const float4*)&Bs[k][tx << 2];
      const float4 y1 = *(const float4*)&Bs[k][64 + (tx << 2)];
      const float ar[8] = {x0.x, x0.y, x0.z, x0.w, x1.x, x1.y, x1.z, x1.w};
      const float br[8] = {y0.x, y0.y, y0.z, y0.w, y1.x, y1.y, y1.z, y1.w};
#pragma unroll
      for (int i = 0; i < 8; ++i)
#pragma unroll
        for (int j = 0; j < 8; ++j) acc[i][j] = fmaf(ar[i], br[j], acc[i][j]);
    }
  }
#pragma unroll
  for (int i = 0; i < 8; ++i) {
    const int m = bm + ((i < 4) ? ((ty << 2) + i) : (64 + (ty << 2) + i - 4));
    float* op0 = Ob + (size_t)m * CDIM + bc + (tx << 2);
    float* op1 = Ob + (size_t)m * CDIM + bc + 64 + (tx << 2);
    float4 o0, o1;
    o0.x = acc[i][0]; o0.y = acc[i][1]; o0.z = acc[i][2]; o0.w = acc[i][3];
    o1.x = acc[i][4]; o1.y = acc[i][5]; o1.z = acc[i][6]; o1.w = acc[i][7];
    *(float4*)op0 = o0;
    *(float4*)op1 = o1;
  }
}

// ---------------- launch ----------------
extern "C" void kernel_launch(void* const* d_in, const int* in_sizes, int n_in,
                              void* d_out, int out_size, void* d_ws,
                              size_t ws_size, hipStream_t stream) {
  const float* query   = (const float*)d_in[0];
  const float* context = (const float*)d_in[1];
  const float* eps     = (const float*)d_in[2];
  const float* Wq      = (const float*)d_in[3];
  const float* bq      = (const float*)d_in[4];
  const float* Wk      = (const float*)d_in[5];
  const float* bk      = (const float*)d_in[6];
  const float* Wv      = (const float*)d_in[7];
  const float* bv      = (const float*)d_in[8];
  const float* Wo      = (const float*)d_in[9];
  const float* bo      = (const float*)d_in[10];
  const float* ln_k_g  = (const float*)d_in[11];
  const float* ln_k_b  = (const float*)d_in[12];
  const float* ln_v_g  = (const float*)d_in[13];
  const float* ln_v_b  = (const float*)d_in[14];
  const float* gate    = (const float*)d_in[15];

  // ---- workspace map, NEED = 189,267,968 B. Lifetimes ([step..step]):
  //  @0          ctxF f16 25.2M [1..2]; then qF @0 + q2F @12582912 [5..6]
  //  @25165824   wkvF f16 4.7M [1..2]
  //  @29884416   kRawF16 25.2M [2..3]; then Obuf f32 25.2M [8..9]
  //  @55050240   kmuF f16 25.2M [3..6]
  //  @80216064   kvarF f16 25.2M [2..6]   (vvarF = kvarF + 12,582,912 halves)
  //  @105381888  vvarF f16 25.2M [2..4]; then S/attn f16 33.5M [6..8]
  //  @138936320  vmuRaw/Vs f32 50.3M [2..8]
  const size_t NEED = 189267968ull;
  if (ws_size < NEED) return;  // fail safely (no OOB writes)
  char* wsb = (char*)d_ws;
  _Float16* ctxF  = (_Float16*)(wsb);
  _Float16* qF    = (_Float16*)(wsb);
  _Float16* q2F   = (_Float16*)(wsb + 12582912);
  _Float16* wkvF  = (_Float16*)(wsb + 25165824);
  _Float16* kRawF = (_Float16*)(wsb + 29884416);
  float*    Obuf  = (float*)(wsb + 29884416);
  _Float16* kmuF  = (_Float16*)(wsb + 55050240);
  _Float16* kvarF = (_Float16*)(wsb + 80216064);
  _Float16* vvarF = (_Float16*)(wsb + 105381888);
  _Float16* Sf    = (_Float16*)(wsb + 105381888);
  float*    vmuB  = (float*)(wsb + 138936320);

  const dim3 blk(256);
  auto sgrid = [](int n4) {
    int g = (n4 + 255) / 256;
    return dim3(g > 2048 ? 2048 : g);
  };
  // 1. upfront fp16 conversion: context, [Wk;Wv] stacked
  cvt16<<<sgrid(3145728), blk, 0, stream>>>(context, ctxF, 3145728);
  cvt16<<<sgrid(294912), blk, 0, stream>>>(Wk, wkvF, 294912);
  cvt16<<<sgrid(294912), blk, 0, stream>>>(Wv, wkvF + 1179648, 294912);
  // 2. fused K+V projection (N=3072): kRawF, kvarF, vmuB, vvarF
  hgemm_nt<1, 7><<<dim3(24, 128, 1), blk, 0, stream>>>(
      ctxF, wkvF, bk, vmuB, 16384, 3072, 768, 0, 0, 12582912,
      kRawF, kvarF, bv, nullptr);
  // 3. K LN -> kmuF fp16
  ln_post_k<<<dim3(16384), blk, 0, stream>>>(kRawF, ln_k_g, ln_k_b, kmuF);
  // 4. V post: Vs = LN(vmu) + sqrt(vvar)*eps, in-place fp32
  ln_post_v<<<dim3(16384), blk, 0, stream>>>(vmuB, vvarF, ln_v_g, ln_v_b, eps);
  // 5. Q proj (fp32 src): qF = fp16(Q), q2F = fp16(Q^2)
  hgemm_nt<0, 1><<<dim3(6, 64, 1), blk, 0, stream>>>(
      query, Wq, bq, nullptr, 8192, 768, 768, 0, 0, 0, qF, q2F, nullptr,
      nullptr);
  // 6. fused scores -> Sf fp16 (batched z=8)
  scores_fused<<<dim3(16, 8, 8), blk, 0, stream>>>(qF, q2F, kmuF, kvarF, Sf);
  // 7. softmax rows fp16, in place -> attn
  softmax_rows_f16<<<dim3(8192), blk, 0, stream>>>(Sf);
  // 8. O = attn @ Vs -> Obuf fp32
  gemm_nn_av<<<dim3(6, 8, 8), blk, 0, stream>>>(Sf, vmuB, Obuf);
  // 9. final: d_out = g*(O @ Wo^T + bo) + (1-g)*query
  hgemm_nt<0, 5><<<dim3(6, 64, 1), blk, 0, stream>>>(
      Obuf, Wo, bo, (float*)d_out, 8192, 768, 768, 0, 0, 0, nullptr, nullptr,
      query, gate);
}